// Round 7
// baseline (2149.545 us; speedup 1.0000x reference)
//
#include <hip/hip_runtime.h>

// Fused Conv1d(k=3,pad=1) + BN(inference) + 4-step LIF + residual.
// x: (L=2048, TB=128, D=128) f32. conv_w: (D,D,3). out: (L,TB,D) f32.
//
// R9 = R7 geometry (LT=64, JT=8, ob=4, transposed conflict-free ws reads)
// with the weight-staging SCATTER fixed: a prep kernel pre-transposes w
// into workspace in the exact LDS image order, so staging loads are fully
// coalesced (were 32 lines x 6KB stride per wave-load = the invariant
// stall R3..R8 all shared). Tile it+1 loads are issued BEFORE tile it's
// compute (issue-early / write-late); between barriers only 3 ds_writes
// remain. Per-o FMA order identical to R3/R7 (absmax must stay 0.0).

constexpr int L   = 2048;
constexpr int NTB = 128;
constexpr int D   = 128;
constexpr int T   = 4;
constexpr int LT  = 64;        // l-tile per block
constexpr int NP  = LT + 2;    // 66 staged positions (halo)
constexpr int JT  = 8;         // l-positions per thread (2 groups x 8 per wave)

// ---- prep: wt[it][(oo*6+f)*32+qq] (float4) = w[(4qq+oo)][it*8+f4 slice] ----
__global__ void transpose_w(const float* __restrict__ w, float* __restrict__ wt) {
    const int i = blockIdx.x * 256 + threadIdx.x;   // float4 index, [0, 16*768)
    if (i >= 16 * 768) return;
    const int it = i / 768;
    const int d  = i - it * 768;
    const int qq = d & 31;
    const int m  = d >> 5;        // oo*6 + f
    const int oo = m / 6;
    const int f  = m - 6 * oo;
    const float4 val = *((const float4*)(w + (4 * qq + oo) * (D * 3) + it * 24 + f * 4));
    ((float4*)wt)[i] = val;
}

__global__ __launch_bounds__(256, 3)
void snn_conv_lif(const float* __restrict__ x, const float* __restrict__ wt,
                  const float* __restrict__ gamma, const float* __restrict__ beta,
                  const float* __restrict__ mean, const float* __restrict__ var,
                  float* __restrict__ out) {
    __shared__ float xs[NP * D];        // 33792 B
    __shared__ float ws[768 * 4];       // 12288 B: [(oo*6+f)*32+qq] float4 (total 46080 B)

    const int tid = threadIdx.x;
    const int b   = blockIdx.x & 31;
    const int lt  = blockIdx.x >> 5;
    const int l0  = lt * LT;
    const int q4  = tid & 31;                                 // o-quad
    const int p0  = (tid >> 6) * 16 + ((tid >> 5) & 1) * JT;  // l-group base
    const float4* wt4 = (const float4*)wt;

    float sc[4], bi[4];
    {
        const float4 g4 = ((const float4*)gamma)[q4];
        const float4 b4 = ((const float4*)beta)[q4];
        const float4 m4 = ((const float4*)mean)[q4];
        const float4 v4 = ((const float4*)var)[q4];
        const float gg[4] = {g4.x, g4.y, g4.z, g4.w};
        const float bb[4] = {b4.x, b4.y, b4.z, b4.w};
        const float mm[4] = {m4.x, m4.y, m4.z, m4.w};
        const float vv[4] = {v4.x, v4.y, v4.z, v4.w};
        #pragma unroll
        for (int oo = 0; oo < 4; ++oo) {
            sc[oo] = gg[oo] / sqrtf(vv[oo] + 1e-5f);
            bi[oo] = bb[oo] - mm[oo] * sc[oo];
        }
    }

    float v[4][JT];
    #pragma unroll
    for (int oo = 0; oo < 4; ++oo)
        #pragma unroll
        for (int j = 0; j < JT; ++j) v[oo][j] = 0.f;

    #pragma unroll 1
    for (int t = 0; t < T; ++t) {
        const int n = t * 32 + b;

        // issue tile-0 weight loads early (coalesced: lanes consecutive)
        float4 wp[3];
        #pragma unroll
        for (int r = 0; r < 3; ++r) wp[r] = wt4[tid + r * 256];

        __syncthreads();   // previous t's xs/ws readers done
        // ---- stage x rows (coalesced) ----
        for (int idx = tid; idx < NP * 32; idx += 256) {
            const int p = idx >> 5, c = idx & 31;
            const int l = l0 - 1 + p;
            float4 val = make_float4(0.f, 0.f, 0.f, 0.f);
            if (l >= 0 && l < L)
                val = ((const float4*)x)[(l * NTB + n) * (D / 4) + c];
            ((float4*)xs)[p * (D / 4) + c] = val;
        }
        // ---- write weight tile 0 ----
        #pragma unroll
        for (int r = 0; r < 3; ++r) ((float4*)ws)[tid + r * 256] = wp[r];
        __syncthreads();   // xs + ws ready

        float a[4][JT];
        #pragma unroll
        for (int oo = 0; oo < 4; ++oo)
            #pragma unroll
            for (int j = 0; j < JT; ++j) a[oo][j] = 0.f;

        #pragma unroll 1
        for (int it = 0; it < 16; ++it) {
            // issue next tile's loads BEFORE compute (hidden under FMAs)
            if (it < 15) {
                #pragma unroll
                for (int r = 0; r < 3; ++r)
                    wp[r] = wt4[(it + 1) * 768 + tid + r * 256];
            }

            #pragma unroll
            for (int i4 = 0; i4 < 2; ++i4) {
                float4 W0[4], W1[4], W2[4];
                #pragma unroll
                for (int oo = 0; oo < 4; ++oo) {
                    const float* wpt = ws + ((oo * 6 + i4 * 3) * 32 + q4) * 4;
                    W0[oo] = *((const float4*)(wpt));
                    W1[oo] = *((const float4*)(wpt + 128));
                    W2[oo] = *((const float4*)(wpt + 256));
                }

                const int ii = it * 2 + i4;
                const float4* xcol = (const float4*)xs + ii;   // channel-group ii
                float4 xa = xcol[(p0 + 0) * 32];
                float4 xb = xcol[(p0 + 1) * 32];
                #pragma unroll
                for (int j = 0; j < JT; ++j) {
                    const float4 xc = xcol[(p0 + j + 2) * 32];
                    #pragma unroll
                    for (int oo = 0; oo < 4; ++oo) {
                        float s = a[oo][j];
                        const float4 w0 = W0[oo], w1 = W1[oo], w2 = W2[oo];
                        s = fmaf(xa.x, w0.x, s);   // k=0, i+0
                        s = fmaf(xa.y, w0.w, s);   // k=0, i+1
                        s = fmaf(xa.z, w1.z, s);   // k=0, i+2
                        s = fmaf(xa.w, w2.y, s);   // k=0, i+3
                        s = fmaf(xb.x, w0.y, s);   // k=1, i+0
                        s = fmaf(xb.y, w1.x, s);   // k=1, i+1
                        s = fmaf(xb.z, w1.w, s);   // k=1, i+2
                        s = fmaf(xb.w, w2.z, s);   // k=1, i+3
                        s = fmaf(xc.x, w0.z, s);   // k=2, i+0
                        s = fmaf(xc.y, w1.y, s);   // k=2, i+1
                        s = fmaf(xc.z, w2.x, s);   // k=2, i+2
                        s = fmaf(xc.w, w2.w, s);   // k=2, i+3
                        a[oo][j] = s;
                    }
                    xa = xb; xb = xc;
                }
            }

            if (it < 15) {
                __syncthreads();   // all waves done reading ws
                #pragma unroll
                for (int r = 0; r < 3; ++r) ((float4*)ws)[tid + r * 256] = wp[r];
                __syncthreads();   // ws holds tile it+1
            }
        }

        // ---- BN + LIF step + residual + store (float4 over the o-quad) ----
        #pragma unroll
        for (int j = 0; j < JT; ++j) {
            const float4 res = ((const float4*)xs)[(p0 + j + 1) * 32 + q4];
            const float rr[4] = {res.x, res.y, res.z, res.w};
            float ov[4];
            #pragma unroll
            for (int oo = 0; oo < 4; ++oo) {
                const float y = fmaf(a[oo][j], sc[oo], bi[oo]);
                const float h = 0.5f * (v[oo][j] + y);     // v + (y - v)/tau, tau=2
                const bool fire = (h >= 1.0f);
                v[oo][j] = fire ? 0.0f : h;                // hard reset
                ov[oo] = rr[oo] + (fire ? 1.0f : 0.0f);
            }
            const int l = l0 + p0 + j;
            ((float4*)out)[(l * NTB + n) * 32 + q4] =
                make_float4(ov[0], ov[1], ov[2], ov[3]);
        }
    }
}

extern "C" void kernel_launch(void* const* d_in, const int* in_sizes, int n_in,
                              void* d_out, int out_size, void* d_ws, size_t ws_size,
                              hipStream_t stream) {
    const float* x     = (const float*)d_in[0];
    const float* w     = (const float*)d_in[1];
    const float* gamma = (const float*)d_in[2];
    const float* beta  = (const float*)d_in[3];
    const float* mean  = (const float*)d_in[4];
    const float* var   = (const float*)d_in[5];
    float* out = (float*)d_out;
    float* wt  = (float*)d_ws;    // 196608 B of workspace

    transpose_w<<<dim3(48), dim3(256), 0, stream>>>(w, wt);

    dim3 grid((L / LT) * 32);   // 32 l-tiles x 32 b values = 1024 blocks
    dim3 block(256);
    snn_conv_lif<<<grid, block, 0, stream>>>(x, wt, gamma, beta, mean, var, out);
}

// Round 8
// 617.905 us; speedup vs baseline: 3.4788x; 3.4788x over previous
//
#include <hip/hip_runtime.h>

// Fused Conv1d(k=3,pad=1) + BN(inference) + 4-step LIF + residual.
// x: (L=2048, TB=128, D=128) f32. conv_w: (D,D,3). out: (L,TB,D) f32.
//
// R10 = R9 (pre-transposed wt in workspace -> coalesced staging, issue-early
// write-late weight pipeline) with the scratch-demotion bug fixed: the
// prefetch loads are now UNCONDITIONAL with a clamped tile index.
// (R6 and R9 both proved: hipcc demotes conditionally-assigned register
// arrays with long live ranges to scratch -> GBs of HBM spill traffic.)
// it=15 harmlessly re-loads/re-writes tile 15. Everything else identical
// to R9/R7; per-o FMA order identical to R3 (absmax must stay 0.0).

constexpr int L   = 2048;
constexpr int NTB = 128;
constexpr int D   = 128;
constexpr int T   = 4;
constexpr int LT  = 64;        // l-tile per block
constexpr int NP  = LT + 2;    // 66 staged positions (halo)
constexpr int JT  = 8;         // l-positions per thread (2 groups x 8 per wave)

// ---- prep: wt[it][(oo*6+f)*32+qq] (float4) = w[(4qq+oo)][it*8+f4 slice] ----
__global__ void transpose_w(const float* __restrict__ w, float* __restrict__ wt) {
    const int i = blockIdx.x * 256 + threadIdx.x;   // float4 index, [0, 16*768)
    if (i >= 16 * 768) return;
    const int it = i / 768;
    const int d  = i - it * 768;
    const int qq = d & 31;
    const int m  = d >> 5;        // oo*6 + f
    const int oo = m / 6;
    const int f  = m - 6 * oo;
    const float4 val = *((const float4*)(w + (4 * qq + oo) * (D * 3) + it * 24 + f * 4));
    ((float4*)wt)[i] = val;
}

__global__ __launch_bounds__(256, 3)
void snn_conv_lif(const float* __restrict__ x, const float* __restrict__ wt,
                  const float* __restrict__ gamma, const float* __restrict__ beta,
                  const float* __restrict__ mean, const float* __restrict__ var,
                  float* __restrict__ out) {
    __shared__ float xs[NP * D];        // 33792 B
    __shared__ float ws[768 * 4];       // 12288 B: [(oo*6+f)*32+qq] float4 (total 46080 B)

    const int tid = threadIdx.x;
    const int b   = blockIdx.x & 31;
    const int lt  = blockIdx.x >> 5;
    const int l0  = lt * LT;
    const int q4  = tid & 31;                                 // o-quad
    const int p0  = (tid >> 6) * 16 + ((tid >> 5) & 1) * JT;  // l-group base
    const float4* wt4 = (const float4*)wt;

    float sc[4], bi[4];
    {
        const float4 g4 = ((const float4*)gamma)[q4];
        const float4 b4 = ((const float4*)beta)[q4];
        const float4 m4 = ((const float4*)mean)[q4];
        const float4 v4 = ((const float4*)var)[q4];
        const float gg[4] = {g4.x, g4.y, g4.z, g4.w};
        const float bb[4] = {b4.x, b4.y, b4.z, b4.w};
        const float mm[4] = {m4.x, m4.y, m4.z, m4.w};
        const float vv[4] = {v4.x, v4.y, v4.z, v4.w};
        #pragma unroll
        for (int oo = 0; oo < 4; ++oo) {
            sc[oo] = gg[oo] / sqrtf(vv[oo] + 1e-5f);
            bi[oo] = bb[oo] - mm[oo] * sc[oo];
        }
    }

    float v[4][JT];
    #pragma unroll
    for (int oo = 0; oo < 4; ++oo)
        #pragma unroll
        for (int j = 0; j < JT; ++j) v[oo][j] = 0.f;

    #pragma unroll 1
    for (int t = 0; t < T; ++t) {
        const int n = t * 32 + b;

        // issue tile-0 weight loads early (coalesced: lanes consecutive)
        float4 wp[3];
        #pragma unroll
        for (int r = 0; r < 3; ++r) wp[r] = wt4[tid + r * 256];

        __syncthreads();   // previous t's xs/ws readers done
        // ---- stage x rows (coalesced) ----
        for (int idx = tid; idx < NP * 32; idx += 256) {
            const int p = idx >> 5, c = idx & 31;
            const int l = l0 - 1 + p;
            float4 val = make_float4(0.f, 0.f, 0.f, 0.f);
            if (l >= 0 && l < L)
                val = ((const float4*)x)[(l * NTB + n) * (D / 4) + c];
            ((float4*)xs)[p * (D / 4) + c] = val;
        }
        // ---- write weight tile 0 ----
        #pragma unroll
        for (int r = 0; r < 3; ++r) ((float4*)ws)[tid + r * 256] = wp[r];
        __syncthreads();   // xs + ws ready

        float a[4][JT];
        #pragma unroll
        for (int oo = 0; oo < 4; ++oo)
            #pragma unroll
            for (int j = 0; j < JT; ++j) a[oo][j] = 0.f;

        #pragma unroll 1
        for (int it = 0; it < 16; ++it) {
            // issue next tile's loads BEFORE compute, UNCONDITIONALLY
            // (clamped index; guarded loads get demoted to scratch)
            const int itn = (it < 15) ? (it + 1) : 15;
            #pragma unroll
            for (int r = 0; r < 3; ++r)
                wp[r] = wt4[itn * 768 + tid + r * 256];

            #pragma unroll
            for (int i4 = 0; i4 < 2; ++i4) {
                float4 W0[4], W1[4], W2[4];
                #pragma unroll
                for (int oo = 0; oo < 4; ++oo) {
                    const float* wpt = ws + ((oo * 6 + i4 * 3) * 32 + q4) * 4;
                    W0[oo] = *((const float4*)(wpt));
                    W1[oo] = *((const float4*)(wpt + 128));
                    W2[oo] = *((const float4*)(wpt + 256));
                }

                const int ii = it * 2 + i4;
                const float4* xcol = (const float4*)xs + ii;   // channel-group ii
                float4 xa = xcol[(p0 + 0) * 32];
                float4 xb = xcol[(p0 + 1) * 32];
                #pragma unroll
                for (int j = 0; j < JT; ++j) {
                    const float4 xc = xcol[(p0 + j + 2) * 32];
                    #pragma unroll
                    for (int oo = 0; oo < 4; ++oo) {
                        float s = a[oo][j];
                        const float4 w0 = W0[oo], w1 = W1[oo], w2 = W2[oo];
                        s = fmaf(xa.x, w0.x, s);   // k=0, i+0
                        s = fmaf(xa.y, w0.w, s);   // k=0, i+1
                        s = fmaf(xa.z, w1.z, s);   // k=0, i+2
                        s = fmaf(xa.w, w2.y, s);   // k=0, i+3
                        s = fmaf(xb.x, w0.y, s);   // k=1, i+0
                        s = fmaf(xb.y, w1.x, s);   // k=1, i+1
                        s = fmaf(xb.z, w1.w, s);   // k=1, i+2
                        s = fmaf(xb.w, w2.z, s);   // k=1, i+3
                        s = fmaf(xc.x, w0.z, s);   // k=2, i+0
                        s = fmaf(xc.y, w1.y, s);   // k=2, i+1
                        s = fmaf(xc.z, w2.x, s);   // k=2, i+2
                        s = fmaf(xc.w, w2.w, s);   // k=2, i+3
                        a[oo][j] = s;
                    }
                    xa = xb; xb = xc;
                }
            }

            // write tile itn (it=15 rewrites tile 15 with identical data)
            __syncthreads();   // all waves done reading ws
            #pragma unroll
            for (int r = 0; r < 3; ++r) ((float4*)ws)[tid + r * 256] = wp[r];
            __syncthreads();   // ws holds tile itn
        }

        // ---- BN + LIF step + residual + store (float4 over the o-quad) ----
        #pragma unroll
        for (int j = 0; j < JT; ++j) {
            const float4 res = ((const float4*)xs)[(p0 + j + 1) * 32 + q4];
            const float rr[4] = {res.x, res.y, res.z, res.w};
            float ov[4];
            #pragma unroll
            for (int oo = 0; oo < 4; ++oo) {
                const float y = fmaf(a[oo][j], sc[oo], bi[oo]);
                const float h = 0.5f * (v[oo][j] + y);     // v + (y - v)/tau, tau=2
                const bool fire = (h >= 1.0f);
                v[oo][j] = fire ? 0.0f : h;                // hard reset
                ov[oo] = rr[oo] + (fire ? 1.0f : 0.0f);
            }
            const int l = l0 + p0 + j;
            ((float4*)out)[(l * NTB + n) * 32 + q4] =
                make_float4(ov[0], ov[1], ov[2], ov[3]);
        }
    }
}

extern "C" void kernel_launch(void* const* d_in, const int* in_sizes, int n_in,
                              void* d_out, int out_size, void* d_ws, size_t ws_size,
                              hipStream_t stream) {
    const float* x     = (const float*)d_in[0];
    const float* w     = (const float*)d_in[1];
    const float* gamma = (const float*)d_in[2];
    const float* beta  = (const float*)d_in[3];
    const float* mean  = (const float*)d_in[4];
    const float* var   = (const float*)d_in[5];
    float* out = (float*)d_out;
    float* wt  = (float*)d_ws;    // 196608 B of workspace

    transpose_w<<<dim3(48), dim3(256), 0, stream>>>(w, wt);

    dim3 grid((L / LT) * 32);   // 32 l-tiles x 32 b values = 1024 blocks
    dim3 block(256);
    snn_conv_lif<<<grid, block, 0, stream>>>(x, wt, gamma, beta, mean, var, out);
}